// Round 4
// baseline (1283.632 us; speedup 1.0000x reference)
//
#include <hip/hip_runtime.h>

#define N_NODES 100000
#define N_EDGES 1200000
#define DIM     64
#define N_LAYERS 3
#define N_GRAPHS 512
#define OUTD    192   // 3 * 64, concat layout
#define BN_EPS  1e-5f

#define SCAN_CHUNK 1024
#define NBLK ((N_NODES + SCAN_CHUNK - 1) / SCAN_CHUNK)   // 98

#define NPB 64            // nodes per block in layer_kernel
#define LDS_PITCH 65      // +1 pad -> 2-way bank aliasing only (free)

// ---------------------------------------------------------------------------
// Transpose W1 and W2 (per layer): WT[l][k][j] = W[l][j][k].
__global__ void transpose_w(const float* __restrict__ W1, const float* __restrict__ W2,
                            float* __restrict__ W1T, float* __restrict__ W2T) {
    int idx = blockIdx.x * blockDim.x + threadIdx.x;  // L*64*64
    if (idx >= N_LAYERS * DIM * DIM) return;
    int l = idx >> 12;
    int r = idx & 4095;
    int j = r >> 6;
    int k = r & 63;
    int dstp = (l << 12) + k * DIM + j;
    W1T[dstp] = W1[idx];
    W2T[dstp] = W2[idx];
}

// ---------------------------------------------------------------------------
// Counting-sort of edges by dst (once per call, reused by all 3 layers).
__global__ void hist_kernel(const int* __restrict__ dst, int* __restrict__ counts) {
    int e = blockIdx.x * blockDim.x + threadIdx.x;
    if (e >= N_EDGES) return;
    atomicAdd(&counts[dst[e]], 1);
}

__global__ void scan_partial(const int* __restrict__ C, int* __restrict__ bsum) {
    __shared__ int lds[256];
    int b = blockIdx.x, t = threadIdx.x;
    int base = b * SCAN_CHUNK + t * 4;
    int s = 0;
#pragma unroll
    for (int k = 0; k < 4; ++k) {
        int i = base + k;
        if (i < N_NODES) s += C[i];
    }
    lds[t] = s;
    __syncthreads();
    for (int o = 128; o > 0; o >>= 1) {
        if (t < o) lds[t] += lds[t + o];
        __syncthreads();
    }
    if (t == 0) bsum[b] = lds[0];
}

__global__ void scan_bsum(int* __restrict__ bsum) {
    __shared__ int lds[128];
    int t = threadIdx.x;
    int v = (t < NBLK) ? bsum[t] : 0;
    lds[t] = v;
    __syncthreads();
    for (int o = 1; o < 128; o <<= 1) {
        int add = (t >= o) ? lds[t - o] : 0;
        __syncthreads();
        lds[t] += add;
        __syncthreads();
    }
    if (t < NBLK) bsum[t] = lds[t] - v;   // exclusive
}

__global__ void scan_final(const int* __restrict__ C, const int* __restrict__ bsum,
                           int* __restrict__ O, int* __restrict__ cursor) {
    __shared__ int lds[256];
    int b = blockIdx.x, t = threadIdx.x;
    int base = b * SCAN_CHUNK + t * 4;
    int v[4];
    int s = 0;
#pragma unroll
    for (int k = 0; k < 4; ++k) {
        int i = base + k;
        v[k] = (i < N_NODES) ? C[i] : 0;
        s += v[k];
    }
    lds[t] = s;
    __syncthreads();
    for (int o = 1; o < 256; o <<= 1) {
        int add = (t >= o) ? lds[t - o] : 0;
        __syncthreads();
        lds[t] += add;
        __syncthreads();
    }
    int off = bsum[b] + (lds[t] - s);
#pragma unroll
    for (int k = 0; k < 4; ++k) {
        int i = base + k;
        if (i < N_NODES) {
            O[i] = off;
            cursor[i] = off;
            off += v[k];
            if (i == N_NODES - 1) O[N_NODES] = off;
        }
    }
}

// Pack (src, weight-bits) into ONE int2 -> single 8B scatter store per edge
// (halves the scattered cache lines vs two 4B stores into separate arrays).
__global__ void edge_bin(const int* __restrict__ src, const int* __restrict__ dst,
                         const float* __restrict__ ew,
                         int* __restrict__ cursor,
                         int2* __restrict__ pe) {
    int e = blockIdx.x * blockDim.x + threadIdx.x;
    if (e >= N_EDGES) return;
    int t = dst[e];
    int pos = atomicAdd(&cursor[t], 1);
    pe[pos] = make_int2(src[e], __float_as_int(ew[e]));
}

// ---------------------------------------------------------------------------
// Fused layer: gather (+x fused) -> LDS -> MLP1 -> relu -> MLP2 -> relu
//  -> global write + fused BN partial stats.
// Block = 512 threads = 8 waves, 64 nodes.
// Gather: wave w aggregates nodes [w*8, w*8+8); node id wave-uniform so edge
// (src,w) pairs are s_loads; x_in[src] row is one coalesced 256B load; edge
// loop unrolled x4 with 4 independent accumulators (4 outstanding loads).
// GEMMs: lane = node, wave = dim-octet (wave-uniform -> weights via s_load).
__global__ void __launch_bounds__(512, 8) layer_kernel(
    const float* __restrict__ x_in, int xstride,
    const int* __restrict__ offsets,
    const int2* __restrict__ pe,
    const float* __restrict__ W1T, const float* __restrict__ b1,
    const float* __restrict__ W2T, const float* __restrict__ b2,
    float* __restrict__ out /* xs base + layer*64, row stride OUTD */,
    double* __restrict__ ssum, double* __restrict__ ssq) {
    __shared__ float lds[NPB * LDS_PITCH];
    int t = threadIdx.x;
    int lane = t & 63;
    int wid = __builtin_amdgcn_readfirstlane(t >> 6);   // wave id 0..7, SGPR
    int nbase = blockIdx.x * NPB;

    // ---- Phase 1: gather (8 nodes per wave) ----
    for (int nn = 0; nn < 8; ++nn) {
        int n = nbase + wid * 8 + nn;        // wave-uniform
        float a0 = 0.0f, a1 = 0.0f, a2 = 0.0f, a3 = 0.0f;
        if (n < N_NODES) {
            int beg = offsets[n];             // s_load
            int end = offsets[n + 1];
            a0 = x_in[(size_t)n * xstride + lane];   // coalesced 256B
            int e = beg;
            for (; e + 4 <= end; e += 4) {
                int2 p0 = pe[e];
                int2 p1 = pe[e + 1];
                int2 p2 = pe[e + 2];
                int2 p3 = pe[e + 3];
                a0 = fmaf(__int_as_float(p0.y), x_in[(size_t)p0.x * xstride + lane], a0);
                a1 = fmaf(__int_as_float(p1.y), x_in[(size_t)p1.x * xstride + lane], a1);
                a2 = fmaf(__int_as_float(p2.y), x_in[(size_t)p2.x * xstride + lane], a2);
                a3 = fmaf(__int_as_float(p3.y), x_in[(size_t)p3.x * xstride + lane], a3);
            }
            for (; e < end; ++e) {
                int2 p = pe[e];
                a1 = fmaf(__int_as_float(p.y), x_in[(size_t)p.x * xstride + lane], a1);
            }
        }
        lds[(wid * 8 + nn) * LDS_PITCH + lane] = (a0 + a1) + (a2 + a3);
    }
    __syncthreads();

    // ---- Stage 1 GEMM: hidden = relu(xin @ W1^T + b1) ----
    // lane = local node, wid = dim octet (uniform).
    float h[8];
#pragma unroll
    for (int jj = 0; jj < 8; ++jj) h[jj] = b1[wid * 8 + jj];
#pragma unroll 4
    for (int k = 0; k < DIM; ++k) {
        float xv = lds[lane * LDS_PITCH + k];
        const float* wr = W1T + k * DIM + wid * 8;   // uniform -> s_load
#pragma unroll
        for (int jj = 0; jj < 8; ++jj) h[jj] = fmaf(xv, wr[jj], h[jj]);
    }
#pragma unroll
    for (int jj = 0; jj < 8; ++jj) h[jj] = fmaxf(h[jj], 0.0f);
    __syncthreads();          // all lds (xin) reads done
#pragma unroll
    for (int jj = 0; jj < 8; ++jj) lds[lane * LDS_PITCH + wid * 8 + jj] = h[jj];
    __syncthreads();

    // ---- Stage 2 GEMM: o = relu(hidden @ W2^T + b2) ----
    float o[8];
#pragma unroll
    for (int jj = 0; jj < 8; ++jj) o[jj] = b2[wid * 8 + jj];
#pragma unroll 4
    for (int k = 0; k < DIM; ++k) {
        float hv = lds[lane * LDS_PITCH + k];
        const float* wr = W2T + k * DIM + wid * 8;
#pragma unroll
        for (int jj = 0; jj < 8; ++jj) o[jj] = fmaf(hv, wr[jj], o[jj]);
    }
    int n = nbase + lane;
    bool valid = (n < N_NODES);
#pragma unroll
    for (int jj = 0; jj < 8; ++jj) o[jj] = fmaxf(o[jj], 0.0f);
    if (valid) {
        float* orow = out + (size_t)n * OUTD + wid * 8;
#pragma unroll
        for (int jj = 0; jj < 8; jj += 4) {
            *(float4*)(orow + jj) = make_float4(o[jj], o[jj + 1], o[jj + 2], o[jj + 3]);
        }
    }

    // ---- Fused BN partial stats: butterfly over 64 lanes (nodes), then one
    // double atomicAdd per dim per block-wave.
#pragma unroll
    for (int jj = 0; jj < 8; ++jj) {
        float v = valid ? o[jj] : 0.0f;
        float vs = v, vq = v * v;
#pragma unroll
        for (int m = 1; m < 64; m <<= 1) {
            vs += __shfl_xor(vs, m);
            vq += __shfl_xor(vq, m);
        }
        if (lane == 0) {
            atomicAdd(&ssum[wid * 8 + jj], (double)vs);
            atomicAdd(&ssq[wid * 8 + jj], (double)vq);
        }
    }
}

// ---------------------------------------------------------------------------
// BN apply (bn_prep folded in): each thread handles 4 dims of one node.
__global__ void bn_kernel(float* __restrict__ h,
                          const double* __restrict__ ssum,
                          const double* __restrict__ ssq,
                          const float* __restrict__ gamma,
                          const float* __restrict__ beta) {
    int idx = blockIdx.x * blockDim.x + threadIdx.x;  // N_NODES * 16
    if (idx >= N_NODES * 16) return;
    int n = idx >> 4;
    int q = idx & 15;
    float sc[4], sh[4];
#pragma unroll
    for (int k = 0; k < 4; ++k) {
        int d = q * 4 + k;
        double mu = ssum[d] / (double)N_NODES;
        float var = (float)(ssq[d] / (double)N_NODES - mu * mu);
        float inv = 1.0f / sqrtf(var + BN_EPS);
        sc[k] = gamma[d] * inv;
        sh[k] = beta[d] - (float)mu * sc[k];
    }
    float* p = h + (size_t)n * OUTD + q * 4;
    float4 v = *(float4*)p;
    v.x = v.x * sc[0] + sh[0];
    v.y = v.y * sc[1] + sh[1];
    v.z = v.z * sc[2] + sh[2];
    v.w = v.w * sc[3] + sh[3];
    *(float4*)p = v;
}

// ---------------------------------------------------------------------------
// Add-pool: 4 blocks per graph, partial sums + one atomicAdd per dim per part.
__global__ void pool_kernel(const float* __restrict__ xs,
                            const int* __restrict__ batch,
                            float* __restrict__ pooled) {
    int g = blockIdx.x;
    int part = blockIdx.y;   // 0..3
    int d = threadIdx.x;     // 0..191
    int start, end;
    {
        int l = 0, h = N_NODES;
        while (l < h) { int m = (l + h) >> 1; if (batch[m] < g) l = m + 1; else h = m; }
        start = l;
    }
    {
        int l = start, h = N_NODES;
        while (l < h) { int m = (l + h) >> 1; if (batch[m] <= g) l = m + 1; else h = m; }
        end = l;
    }
    float acc = 0.0f;
    for (int n = start + part; n < end; n += 4) acc += xs[(size_t)n * OUTD + d];
    atomicAdd(&pooled[(size_t)g * OUTD + d], acc);
}

// ---------------------------------------------------------------------------
extern "C" void kernel_launch(void* const* d_in, const int* in_sizes, int n_in,
                              void* d_out, int out_size, void* d_ws, size_t ws_size,
                              hipStream_t stream) {
    const float* x0    = (const float*)d_in[0];
    const int*   ei    = (const int*)d_in[1];
    const float* ew    = (const float*)d_in[2];
    const int*   batch = (const int*)d_in[3];
    const float* W1    = (const float*)d_in[5];
    const float* b1    = (const float*)d_in[6];
    const float* W2    = (const float*)d_in[7];
    const float* b2    = (const float*)d_in[8];
    const float* gamma = (const float*)d_in[9];
    const float* beta  = (const float*)d_in[10];

    float* pooled = (float*)d_out;                      // [512, 192]
    float* xs     = pooled + (size_t)N_GRAPHS * OUTD;   // [100000, 192]

    // Workspace layout (pe first, 8B aligned; counts..stats is one contiguous
    // zero region so a single memset clears both):
    int2*   pe      = (int2*)d_ws;                         // 9.6 MB
    int*    counts  = (int*)(pe + N_EDGES);                // (N+4) ints
    double* stats   = (double*)(counts + N_NODES + 4);     // 3 layers * 128 doubles
    int*    offsets = (int*)(stats + N_LAYERS * 2 * DIM);  // (N+4) ints
    int*    cursor  = offsets + N_NODES + 4;
    int*    bsum    = cursor + N_NODES + 4;                // 128 ints
    float*  W1T     = (float*)(bsum + 128);                // 48 KB
    float*  W2T     = W1T + N_LAYERS * DIM * DIM;          // 48 KB

    const int* src = ei;
    const int* dst = ei + N_EDGES;

    size_t zero_bytes = (size_t)(N_NODES + 4) * sizeof(int)
                      + (size_t)N_LAYERS * 2 * DIM * sizeof(double);

    transpose_w<<<(N_LAYERS * DIM * DIM + 255) / 256, 256, 0, stream>>>(W1, W2, W1T, W2T);

    // --- edge counting-sort (once per call) ---
    hipMemsetAsync(counts, 0, zero_bytes, stream);
    hist_kernel<<<(N_EDGES + 255) / 256, 256, 0, stream>>>(dst, counts);
    scan_partial<<<NBLK, 256, 0, stream>>>(counts, bsum);
    scan_bsum<<<1, 128, 0, stream>>>(bsum);
    scan_final<<<NBLK, 256, 0, stream>>>(counts, bsum, offsets, cursor);
    edge_bin<<<(N_EDGES + 255) / 256, 256, 0, stream>>>(src, dst, ew, cursor, pe);

    int nblocks = (N_NODES + NPB - 1) / NPB;   // 1563
    for (int i = 0; i < N_LAYERS; ++i) {
        const float* xin = (i == 0) ? x0 : (xs + (size_t)(i - 1) * DIM);
        int xstride = (i == 0) ? DIM : OUTD;
        double* ssum = stats + (size_t)i * 2 * DIM;
        double* ssq  = ssum + DIM;

        layer_kernel<<<nblocks, 512, 0, stream>>>(
            xin, xstride, offsets, pe,
            W1T + (size_t)i * DIM * DIM, b1 + (size_t)i * DIM,
            W2T + (size_t)i * DIM * DIM, b2 + (size_t)i * DIM,
            xs + (size_t)i * DIM, ssum, ssq);

        bn_kernel<<<(N_NODES * 16 + 255) / 256, 256, 0, stream>>>(
            xs + (size_t)i * DIM, ssum, ssq,
            gamma + (size_t)i * DIM, beta + (size_t)i * DIM);
    }

    hipMemsetAsync(pooled, 0, (size_t)N_GRAPHS * OUTD * sizeof(float), stream);
    dim3 pgrid(N_GRAPHS, 4);
    pool_kernel<<<pgrid, OUTD, 0, stream>>>(xs, batch, pooled);
}

// Round 5
// 755.700 us; speedup vs baseline: 1.6986x; 1.6986x over previous
//
#include <hip/hip_runtime.h>

#define N_NODES 100000
#define N_EDGES 1200000
#define DIM     64
#define N_LAYERS 3
#define N_GRAPHS 512
#define OUTD    192   // 3 * 64, concat layout
#define BN_EPS  1e-5f

#define SCAN_CHUNK 1024
#define NBLK ((N_NODES + SCAN_CHUNK - 1) / SCAN_CHUNK)   // 98

#define NPB 64            // nodes per block in layer_kernel
#define LDS_PITCH 65      // +1 pad -> 2-way bank aliasing only (free)
#define NLBLK ((N_NODES + NPB - 1) / NPB)                // 1563

// ---------------------------------------------------------------------------
// Transpose W1/W2 (per layer): WT[l][k][j] = W[l][j][k]. Also writes the
// identity affine block (scale=1, shift=0) used by layer 0.
__global__ void transpose_w(const float* __restrict__ W1, const float* __restrict__ W2,
                            float* __restrict__ W1T, float* __restrict__ W2T,
                            float* __restrict__ idaff) {
    int idx = blockIdx.x * blockDim.x + threadIdx.x;  // L*64*64
    if (idx < 128) idaff[idx] = (idx < 64) ? 1.0f : 0.0f;
    if (idx >= N_LAYERS * DIM * DIM) return;
    int l = idx >> 12;
    int r = idx & 4095;
    int j = r >> 6;
    int k = r & 63;
    int dstp = (l << 12) + k * DIM + j;
    W1T[dstp] = W1[idx];
    W2T[dstp] = W2[idx];
}

// ---------------------------------------------------------------------------
// Histogram of dst + per-node incoming-weight sum (wsum, used for BN folding).
__global__ void hist_kernel(const int* __restrict__ dst, const float* __restrict__ ew,
                            int* __restrict__ counts, float* __restrict__ wsumf) {
    int e = blockIdx.x * blockDim.x + threadIdx.x;
    if (e >= N_EDGES) return;
    int t = dst[e];
    atomicAdd(&counts[t], 1);
    atomicAdd(&wsumf[t], ew[e]);
}

__global__ void scan_partial(const int* __restrict__ C, int* __restrict__ bsum) {
    __shared__ int lds[256];
    int b = blockIdx.x, t = threadIdx.x;
    int base = b * SCAN_CHUNK + t * 4;
    int s = 0;
#pragma unroll
    for (int k = 0; k < 4; ++k) {
        int i = base + k;
        if (i < N_NODES) s += C[i];
    }
    lds[t] = s;
    __syncthreads();
    for (int o = 128; o > 0; o >>= 1) {
        if (t < o) lds[t] += lds[t + o];
        __syncthreads();
    }
    if (t == 0) bsum[b] = lds[0];
}

__global__ void scan_bsum(int* __restrict__ bsum) {
    __shared__ int lds[128];
    int t = threadIdx.x;
    int v = (t < NBLK) ? bsum[t] : 0;
    lds[t] = v;
    __syncthreads();
    for (int o = 1; o < 128; o <<= 1) {
        int add = (t >= o) ? lds[t - o] : 0;
        __syncthreads();
        lds[t] += add;
        __syncthreads();
    }
    if (t < NBLK) bsum[t] = lds[t] - v;   // exclusive
}

__global__ void scan_final(const int* __restrict__ C, const int* __restrict__ bsum,
                           int* __restrict__ O, int* __restrict__ cursor) {
    __shared__ int lds[256];
    int b = blockIdx.x, t = threadIdx.x;
    int base = b * SCAN_CHUNK + t * 4;
    int v[4];
    int s = 0;
#pragma unroll
    for (int k = 0; k < 4; ++k) {
        int i = base + k;
        v[k] = (i < N_NODES) ? C[i] : 0;
        s += v[k];
    }
    lds[t] = s;
    __syncthreads();
    for (int o = 1; o < 256; o <<= 1) {
        int add = (t >= o) ? lds[t - o] : 0;
        __syncthreads();
        lds[t] += add;
        __syncthreads();
    }
    int off = bsum[b] + (lds[t] - s);
#pragma unroll
    for (int k = 0; k < 4; ++k) {
        int i = base + k;
        if (i < N_NODES) {
            O[i] = off;
            cursor[i] = off;
            off += v[k];
            if (i == N_NODES - 1) O[N_NODES] = off;
        }
    }
}

// Pack (src, weight-bits) into ONE int2 -> single 8B scatter store per edge.
__global__ void edge_bin(const int* __restrict__ src, const int* __restrict__ dst,
                         const float* __restrict__ ew,
                         int* __restrict__ cursor,
                         int2* __restrict__ pe) {
    int e = blockIdx.x * blockDim.x + threadIdx.x;
    if (e >= N_EDGES) return;
    int t = dst[e];
    int pos = atomicAdd(&cursor[t], 1);
    pe[pos] = make_int2(src[e], __float_as_int(ew[e]));
}

// ---------------------------------------------------------------------------
// Fused layer (R3-proven core): gather(+x, +input-BN-affine) -> LDS -> MLP1
// -> relu -> MLP2 -> relu -> global write + per-block BN stat partials.
// Block = 256 threads = 4 waves, 64 nodes.
// Input affine: BN of the PREVIOUS layer folded in algebraically:
//   agg_bn = sc*(h[n] + sum w*h[s]) + sh*(1 + wsum[n]).
// Layer 0 uses the identity affine (sc=1, sh=0).
__global__ void __launch_bounds__(256) layer_kernel(
    const float* __restrict__ x_in, int xstride,
    const int* __restrict__ offsets,
    const int2* __restrict__ pe,
    const float* __restrict__ wsum,
    const float* __restrict__ affine /* [128]: scale|shift of input */,
    const float* __restrict__ W1T, const float* __restrict__ b1,
    const float* __restrict__ W2T, const float* __restrict__ b2,
    float* __restrict__ out /* xs base + layer*64, row stride OUTD */,
    float* __restrict__ pstat /* [NLBLK][128]: sum|sumsq partials */) {
    __shared__ float lds[NPB * LDS_PITCH];
    int t = threadIdx.x;
    int lane = t & 63;
    int wid = __builtin_amdgcn_readfirstlane(t >> 6);   // wave id 0..3, SGPR
    int nbase = blockIdx.x * NPB;

    float sc_in = affine[lane];          // coalesced 256B, once
    float sh_in = affine[64 + lane];

    // ---- Phase 1: gather (16 nodes per wave, node id wave-uniform) ----
    for (int nn = 0; nn < 16; ++nn) {
        int n = nbase + wid * 16 + nn;
        float acc = 0.0f;
        if (n < N_NODES) {
            int beg = offsets[n];             // s_load
            int end = offsets[n + 1];
            acc = x_in[(size_t)n * xstride + lane];   // coalesced 256B
            float a1 = 0.0f;
            int e = beg;
            for (; e + 2 <= end; e += 2) {
                int2 p0 = pe[e];
                int2 p1 = pe[e + 1];
                acc = fmaf(__int_as_float(p0.y), x_in[(size_t)p0.x * xstride + lane], acc);
                a1  = fmaf(__int_as_float(p1.y), x_in[(size_t)p1.x * xstride + lane], a1);
            }
            if (e < end) {
                int2 p = pe[e];
                a1 = fmaf(__int_as_float(p.y), x_in[(size_t)p.x * xstride + lane], a1);
            }
            acc += a1;
            acc = fmaf(sc_in, acc, sh_in * (1.0f + wsum[n]));
        }
        lds[(wid * 16 + nn) * LDS_PITCH + lane] = acc;
    }
    __syncthreads();

    // ---- Stage 1 GEMM: hidden = relu(xin @ W1^T + b1) ----
    // lane = local node, wid = dim quarter (uniform -> weights via s_load).
    float h[16];
#pragma unroll
    for (int jj = 0; jj < 16; ++jj) h[jj] = b1[wid * 16 + jj];
#pragma unroll 4
    for (int k = 0; k < DIM; ++k) {
        float xv = lds[lane * LDS_PITCH + k];
        const float* wr = W1T + k * DIM + wid * 16;
#pragma unroll
        for (int jj = 0; jj < 16; ++jj) h[jj] = fmaf(xv, wr[jj], h[jj]);
    }
#pragma unroll
    for (int jj = 0; jj < 16; ++jj) h[jj] = fmaxf(h[jj], 0.0f);
    __syncthreads();          // all lds (xin) reads done
#pragma unroll
    for (int jj = 0; jj < 16; ++jj) lds[lane * LDS_PITCH + wid * 16 + jj] = h[jj];
    __syncthreads();

    // ---- Stage 2 GEMM: o = relu(hidden @ W2^T + b2) ----
    float o[16];
#pragma unroll
    for (int jj = 0; jj < 16; ++jj) o[jj] = b2[wid * 16 + jj];
#pragma unroll 4
    for (int k = 0; k < DIM; ++k) {
        float hv = lds[lane * LDS_PITCH + k];
        const float* wr = W2T + k * DIM + wid * 16;
#pragma unroll
        for (int jj = 0; jj < 16; ++jj) o[jj] = fmaf(hv, wr[jj], o[jj]);
    }
    int n = nbase + lane;
    bool valid = (n < N_NODES);
#pragma unroll
    for (int jj = 0; jj < 16; ++jj) o[jj] = fmaxf(o[jj], 0.0f);
    if (valid) {
        float* orow = out + (size_t)n * OUTD + wid * 16;
#pragma unroll
        for (int jj = 0; jj < 16; jj += 4) {
            *(float4*)(orow + jj) = make_float4(o[jj], o[jj + 1], o[jj + 2], o[jj + 3]);
        }
    }

    // ---- BN stat partials: butterfly over 64 lanes (nodes); wave `wid` owns
    // dims [wid*16, wid*16+16). Non-atomic coalesced per-block store.
    float my_s = 0.0f, my_q = 0.0f;
#pragma unroll
    for (int jj = 0; jj < 16; ++jj) {
        float v = valid ? o[jj] : 0.0f;
        float vs = v, vq = v * v;
#pragma unroll
        for (int m = 1; m < 64; m <<= 1) {
            vs += __shfl_xor(vs, m);
            vq += __shfl_xor(vq, m);
        }
        if (lane == jj) { my_s = vs; my_q = vq; }
    }
    if (lane < 16) {
        size_t base = (size_t)blockIdx.x * 128 + wid * 16 + lane;
        pstat[base] = my_s;
        pstat[base + 64] = my_q;
    }
}

// ---------------------------------------------------------------------------
// Reduce per-block BN partials -> scale/shift for one layer (bn_prep folded).
// One block of 1024 threads; group g of 128 threads strides over blocks.
__global__ void __launch_bounds__(1024) reduce_stats(
    const float* __restrict__ pstat,
    const float* __restrict__ gamma, const float* __restrict__ beta,
    float* __restrict__ ss /* [128]: scale|shift */) {
    __shared__ double part[8][128];
    __shared__ double tot[128];
    int t = threadIdx.x;
    int d = t & 127;
    int g = t >> 7;
    double s = 0.0;
    for (int b = g; b < NLBLK; b += 8)
        s += (double)pstat[(size_t)b * 128 + d];
    part[g][d] = s;
    __syncthreads();
    if (t < 128) {
        double x = 0.0;
#pragma unroll
        for (int k = 0; k < 8; ++k) x += part[k][d];
        tot[d] = x;
    }
    __syncthreads();
    if (t < 64) {
        double mu = tot[t] / (double)N_NODES;
        double var = tot[64 + t] / (double)N_NODES - mu * mu;
        float inv = (float)(1.0 / sqrt(var + (double)BN_EPS));
        float sc = gamma[t] * inv;
        ss[t] = sc;
        ss[64 + t] = beta[t] - (float)mu * sc;
    }
}

// ---------------------------------------------------------------------------
// Final pass: apply BN affine to xs IN PLACE (all 3 layers at once) and
// add-pool per graph. Grid (512 graphs, 4 parts), block 192 (= one dim each).
// Reads/writes 192-float node rows fully coalesced (768B per row).
__global__ void bn_pool(float* __restrict__ xs,
                        const int* __restrict__ batch,
                        const float* __restrict__ ss /* [3][128] */,
                        float* __restrict__ pooled) {
    int g = blockIdx.x;
    int part = blockIdx.y;   // 0..3
    int d = threadIdx.x;     // 0..191
    int l = d >> 6, dd = d & 63;
    float sc = ss[l * 128 + dd];
    float sh = ss[l * 128 + 64 + dd];
    int start, end;
    {
        int lo = 0, hi = N_NODES;
        while (lo < hi) { int m = (lo + hi) >> 1; if (batch[m] < g) lo = m + 1; else hi = m; }
        start = lo;
    }
    {
        int lo = start, hi = N_NODES;
        while (lo < hi) { int m = (lo + hi) >> 1; if (batch[m] <= g) lo = m + 1; else hi = m; }
        end = lo;
    }
    float acc = 0.0f;
    for (int n = start + part; n < end; n += 4) {
        float* p = xs + (size_t)n * OUTD + d;
        float v = fmaf(*p, sc, sh);
        *p = v;
        acc += v;
    }
    atomicAdd(&pooled[(size_t)g * OUTD + d], acc);
}

// ---------------------------------------------------------------------------
extern "C" void kernel_launch(void* const* d_in, const int* in_sizes, int n_in,
                              void* d_out, int out_size, void* d_ws, size_t ws_size,
                              hipStream_t stream) {
    const float* x0    = (const float*)d_in[0];
    const int*   ei    = (const int*)d_in[1];
    const float* ew    = (const float*)d_in[2];
    const int*   batch = (const int*)d_in[3];
    const float* W1    = (const float*)d_in[5];
    const float* b1    = (const float*)d_in[6];
    const float* W2    = (const float*)d_in[7];
    const float* b2    = (const float*)d_in[8];
    const float* gamma = (const float*)d_in[9];
    const float* beta  = (const float*)d_in[10];

    float* pooled = (float*)d_out;                      // [512, 192]
    float* xs     = pooled + (size_t)N_GRAPHS * OUTD;   // [100000, 192]

    // Workspace layout (counts..wsumf is one contiguous zero region):
    int2*   pe      = (int2*)d_ws;                         // 9.6 MB
    int*    counts  = (int*)(pe + N_EDGES);                // (N+4) ints  [zeroed]
    float*  wsumf   = (float*)(counts + N_NODES + 4);      // (N+4) floats [zeroed]
    int*    offsets = (int*)(wsumf + N_NODES + 4);         // (N+4) ints
    int*    cursor  = offsets + N_NODES + 4;
    int*    bsum    = cursor + N_NODES + 4;                // 128 ints
    float*  W1T     = (float*)(bsum + 128);                // 48 KB
    float*  W2T     = W1T + N_LAYERS * DIM * DIM;          // 48 KB
    float*  idaff   = W2T + N_LAYERS * DIM * DIM;          // 128 floats
    float*  ss      = idaff + 128;                         // 3*128 floats
    float*  pstat   = ss + N_LAYERS * 128;                 // NLBLK*128 floats (800 KB)

    const int* src = ei;
    const int* dst = ei + N_EDGES;

    size_t zero_bytes = (size_t)(N_NODES + 4) * (sizeof(int) + sizeof(float));

    transpose_w<<<(N_LAYERS * DIM * DIM + 255) / 256, 256, 0, stream>>>(
        W1, W2, W1T, W2T, idaff);

    // --- edge counting-sort + wsum (once per call) ---
    hipMemsetAsync(counts, 0, zero_bytes, stream);
    hist_kernel<<<(N_EDGES + 255) / 256, 256, 0, stream>>>(dst, ew, counts, wsumf);
    scan_partial<<<NBLK, 256, 0, stream>>>(counts, bsum);
    scan_bsum<<<1, 128, 0, stream>>>(bsum);
    scan_final<<<NBLK, 256, 0, stream>>>(counts, bsum, offsets, cursor);
    edge_bin<<<(N_EDGES + 255) / 256, 256, 0, stream>>>(src, dst, ew, cursor, pe);

    for (int i = 0; i < N_LAYERS; ++i) {
        const float* xin = (i == 0) ? x0 : (xs + (size_t)(i - 1) * DIM);
        int xstride = (i == 0) ? DIM : OUTD;
        const float* affine = (i == 0) ? idaff : (ss + (size_t)(i - 1) * 128);

        layer_kernel<<<NLBLK, 256, 0, stream>>>(
            xin, xstride, offsets, pe, wsumf, affine,
            W1T + (size_t)i * DIM * DIM, b1 + (size_t)i * DIM,
            W2T + (size_t)i * DIM * DIM, b2 + (size_t)i * DIM,
            xs + (size_t)i * DIM, pstat);

        reduce_stats<<<1, 1024, 0, stream>>>(
            pstat, gamma + (size_t)i * DIM, beta + (size_t)i * DIM,
            ss + (size_t)i * 128);
    }

    hipMemsetAsync(pooled, 0, (size_t)N_GRAPHS * OUTD * sizeof(float), stream);
    dim3 pgrid(N_GRAPHS, 4);
    bn_pool<<<pgrid, OUTD, 0, stream>>>(xs, batch, ss, pooled);
}